// Round 7
// baseline (46382.791 us; speedup 1.0000x reference)
//
#include <hip/hip_runtime.h>

#define TT 2048
#define BB 64
#define INF 32
#define HH 512
#define OO 32

__device__ __forceinline__ float sigm(float x) {
  return 1.f / (1.f + __expf(-x));
}
__device__ __forceinline__ float tanh_(float x) {
  float e = __expf(2.f * x);
  return 1.f - 2.f / (1.f + e);
}

// Coherent (L1/L2-bypassing) 16B load from the coherence point (IF$).
#define COH_LOAD4(dst, ptr)                                                  \
  asm volatile("global_load_dwordx4 %0, %1, off sc0 sc1"                     \
               : "=v"(dst) : "v"(ptr))

// Bounded spin: legit waits are ~µs; guard guarantees termination even under
// a protocol bug (wrong answer beats wedged GPU).
#define SPIN_LIMIT 20000

// LDS h-buffer: 8 batches x 64 k-groups, each group 8 floats + 4 pad words.
// Measured (R5): SQ_LDS_BANK_CONFLICT == 0 with this layout.
#define HGRP 12
#define HB_STRIDE (64 * HGRP)  // 768 words per batch

// grid = 256 WGs: bg = blockIdx&7 (8 batches each), sl = blockIdx>>3 (16 h-indices each)
// block = 512 thr: wave rg = tid>>6 owns local rows [rg*8, rg*8+8); lane = k-chunk (8 k each)
// local row r in [0,64): gate gc = r>>4, jj = r&15, global row = gc*512 + sl*16 + jj
__global__ __launch_bounds__(512, 2)
void lstm_fused(const float* __restrict__ X,
                const float* __restrict__ h0,
                const float* __restrict__ c0,
                const float* __restrict__ Wih,
                const float* __restrict__ Whh,
                const float* __restrict__ bih,
                const float* __restrict__ bhh,
                const float* __restrict__ Wout,
                const float* __restrict__ bout,
                float* __restrict__ outp,
                float* __restrict__ hT,
                float* __restrict__ cT,
                float* __restrict__ hring,   // [2][64][512] fp32 (coherent-point traffic)
                int* __restrict__ flags)     // [8][32] monotonic, zeroed per launch
{
  const int tid    = threadIdx.x;
  const int rg     = tid >> 6;
  const int lane   = tid & 63;
  const int bg     = blockIdx.x & 7;
  const int sl     = blockIdx.x >> 3;
  const int k0     = lane << 3;
  const int bglob0 = bg << 3;

  __shared__ float gsh[512];                 // gates [r(64)][b(8)]
  __shared__ float hlds[8 * HB_STRIDE];      // staged h, padded (24 KB)

  // ---- persistent weights in registers ----
  float w[8][8];
  float wih[8];
  const int ink = lane & 31;
#pragma unroll
  for (int rr = 0; rr < 8; ++rr) {
    int r = (rg << 3) + rr;
    int grow = ((r >> 4) << 9) + (sl << 4) + (r & 15);
    const float4* wp = (const float4*)(Whh + (size_t)grow * HH + k0);
    float4 a = wp[0], b4 = wp[1];
    w[rr][0] = a.x;  w[rr][1] = a.y;  w[rr][2] = a.z;  w[rr][3] = a.w;
    w[rr][4] = b4.x; w[rr][5] = b4.y; w[rr][6] = b4.z; w[rr][7] = b4.w;
    wih[rr] = Wih[grow * INF + ink];
  }
  float wout[8];
  {
    const float4* wp = (const float4*)(Wout + sl * HH + k0);
    float4 a = wp[0], b4 = wp[1];
    wout[0] = a.x;  wout[1] = a.y;  wout[2] = a.z;  wout[3] = a.w;
    wout[4] = b4.x; wout[5] = b4.y; wout[6] = b4.z; wout[7] = b4.w;
  }
  float bsum, bo = bout[sl];
  {
    int r = (rg << 3) + (lane >> 3);
    int grow = ((r >> 4) << 9) + (sl << 4) + (r & 15);
    bsum = bih[grow] + bhh[grow];
  }

  const bool owner = (tid < 128);
  const int ojj = tid >> 3, ob = tid & 7;
  const int hoff_owner = (bglob0 + ob) * HH + (sl << 4) + ojj;
  float cst = owner ? c0[hoff_owner] : 0.f;

  // cooperative-load mapping: thread handles batch lb, k-group lg
  const int lb = tid >> 6;
  const int lg = tid & 63;

  int* myflags = flags + (bg << 5);

  for (int t = 0; t < TT; ++t) {
    // ---- X prefetch only (no FMAs yet — keep v's live range short) ----
    float xv[4];
    {
      const float* xr = X + (size_t)t * BB * INF + bglob0 * INF + ink;
      const int jb = (lane >= 32) ? 4 : 0;
#pragma unroll
      for (int j = 0; j < 4; ++j) xv[j] = xr[(jb + j) * INF];
    }

    // ---- wait for h_{t-1}: all 32 slices of my bg published step t-1 ----
    if (t > 0 && rg == 0) {
      int f = __hip_atomic_load(&myflags[lane & 31], __ATOMIC_RELAXED,
                                __HIP_MEMORY_SCOPE_AGENT);
      int guard = 0;
      while (__any(f < t)) {
        if (++guard > SPIN_LIMIT) break;   // uniform across wave
        __builtin_amdgcn_s_sleep(1);
        f = __hip_atomic_load(&myflags[lane & 31], __ATOMIC_RELAXED,
                              __HIP_MEMORY_SCOPE_AGENT);
      }
    }
    __syncthreads();  // barrier A: everyone sees flags>=t (via wave 0)

    // ---- cooperative coherent load of h_{t-1} (16 KB once per WG) ----
    {
      const float* hsrc = (t == 0) ? h0 : hring + (size_t)((t - 1) & 1) * BB * HH;
      const float* hp = hsrc + (size_t)(bglob0 + lb) * HH + (lg << 3);
      float4 ha, hb4;
      COH_LOAD4(ha, hp);
      COH_LOAD4(hb4, hp + 4);
      asm volatile("s_waitcnt vmcnt(0)" ::: "memory");
      __builtin_amdgcn_sched_barrier(0);
      float* dst = hlds + lb * HB_STRIDE + lg * HGRP;
      *(float4*)(dst)     = ha;
      *(float4*)(dst + 4) = hb4;
    }
    __syncthreads();  // barrier A2: staged h visible to all waves

    // ---- accumulators live ONLY from here to the gsh store (R4 structure) ----
    float v[64];
#pragma unroll
    for (int i = 0; i < 64; ++i) v[i] = 0.f;
    float oacc = 0.f;

    // ---- recurrent dots: 8 batches x 8 rows x 8 k, LDS-fed register FMAs ----
#pragma unroll
    for (int b = 0; b < 8; ++b) {
      const float4* src = (const float4*)(hlds + b * HB_STRIDE + lane * HGRP);
      float4 a = src[0], b4 = src[1];
      float hk[8] = {a.x, a.y, a.z, a.w, b4.x, b4.y, b4.z, b4.w};
#pragma unroll
      for (int rr = 0; rr < 8; ++rr)
#pragma unroll
        for (int kk = 0; kk < 8; ++kk)
          v[rr * 8 + b] = __fmaf_rn(w[rr][kk], hk[kk], v[rr * 8 + b]);
      if (b == rg) {  // wave-uniform
#pragma unroll
        for (int kk = 0; kk < 8; ++kk) oacc = __fmaf_rn(hk[kk], wout[kk], oacc);
      }
    }

    // ---- input projection (xv regs loaded pre-poll) ----
    {
      const int jb = (lane >= 32) ? 4 : 0;
#pragma unroll
      for (int j = 0; j < 4; ++j)
#pragma unroll
        for (int rr = 0; rr < 8; ++rr)
          v[rr * 8 + jb + j] = __fmaf_rn(wih[rr], xv[j], v[rr * 8 + jb + j]);
    }

    // ---- butterfly reduce over 64 k-chunk lanes; lane ends with idx==lane ----
#pragma unroll
    for (int i = 0; i < 32; ++i) {
      float a = v[i], b = v[i + 32];
      asm("v_permlane32_swap_b32 %0, %1" : "+v"(a), "+v"(b));
      v[i] = a + b;
    }
#pragma unroll
    for (int i = 0; i < 16; ++i) {
      float a = v[i], b = v[i + 16];
      asm("v_permlane16_swap_b32 %0, %1" : "+v"(a), "+v"(b));
      v[i] = a + b;
    }
#pragma unroll
    for (int s = 8; s >= 1; s >>= 1) {
      const bool hi = (lane & s) != 0;
#pragma unroll
      for (int i = 0; i < s; ++i) {
        float sent = hi ? v[i] : v[i + s];
        float keep = hi ? v[i + s] : v[i];
        v[i] = keep + __shfl_xor(sent, s, 64);
      }
    }
    gsh[(rg << 6) + lane] = v[0] + bsum;  // gates[r = rg*8+(lane>>3)][b = lane&7]
    __syncthreads();  // barrier B

    // ---- owners: nonlinearity, c/h update, coherent publish ----
    float* slotp = hring + (size_t)(t & 1) * BB * HH;
    if (owner) {
      float gi = gsh[(ojj << 3) + ob];
      float gf = gsh[((16 + ojj) << 3) + ob];
      float gg = gsh[((32 + ojj) << 3) + ob];
      float go = gsh[((48 + ojj) << 3) + ob];
      float i_ = sigm(gi), f_ = sigm(gf), g_ = tanh_(gg), o_ = sigm(go);
      cst = __fmaf_rn(f_, cst, i_ * g_);
      float hv = o_ * tanh_(cst);
      // write-through to coherence point; no fence needed
      __hip_atomic_store(&slotp[hoff_owner], hv, __ATOMIC_RELAXED,
                         __HIP_MEMORY_SCOPE_AGENT);
      if (t == TT - 1) { hT[hoff_owner] = hv; cT[hoff_owner] = cst; }
    }
    __syncthreads();  // barrier C: drains owners' stores (vmcnt(0) before s_barrier)
    if (tid == 0)
      __hip_atomic_store(&myflags[sl], t + 1, __ATOMIC_RELAXED,
                         __HIP_MEMORY_SCOPE_AGENT);

    // ---- deferred: out-projection reduce (off the inter-WG critical path) ----
#pragma unroll
    for (int s = 32; s >= 1; s >>= 1) oacc += __shfl_xor(oacc, s, 64);
    if (t > 0 && lane == 0)
      outp[(size_t)(t - 1) * BB * OO + (bglob0 + rg) * OO + sl] = oacc + bo;
  }

  // ---- final output projection for h_{TT-1} -> outputs[TT-1] ----
  if (rg == 0) {
    int f = __hip_atomic_load(&myflags[lane & 31], __ATOMIC_RELAXED,
                              __HIP_MEMORY_SCOPE_AGENT);
    int guard = 0;
    while (__any(f < TT)) {
      if (++guard > SPIN_LIMIT) break;
      __builtin_amdgcn_s_sleep(1);
      f = __hip_atomic_load(&myflags[lane & 31], __ATOMIC_RELAXED,
                            __HIP_MEMORY_SCOPE_AGENT);
    }
  }
  __syncthreads();
  {
    const float* hsrc = hring + (size_t)((TT - 1) & 1) * BB * HH;
    const float* hb = hsrc + (size_t)(bglob0 + rg) * HH + k0;
    float4 a, b4;
    COH_LOAD4(a, hb);
    COH_LOAD4(b4, hb + 4);
    asm volatile("s_waitcnt vmcnt(0)" ::: "memory");
    __builtin_amdgcn_sched_barrier(0);
    float oacc = a.x * wout[0] + a.y * wout[1] + a.z * wout[2] + a.w * wout[3]
               + b4.x * wout[4] + b4.y * wout[5] + b4.z * wout[6] + b4.w * wout[7];
#pragma unroll
    for (int s = 32; s >= 1; s >>= 1) oacc += __shfl_xor(oacc, s, 64);
    if (lane == 0)
      outp[(size_t)(TT - 1) * BB * OO + (bglob0 + rg) * OO + sl] = oacc + bo;
  }
}

extern "C" void kernel_launch(void* const* d_in, const int* in_sizes, int n_in,
                              void* d_out, int out_size, void* d_ws, size_t ws_size,
                              hipStream_t stream) {
  const float* X    = (const float*)d_in[0];
  const float* h0   = (const float*)d_in[1];
  const float* c0   = (const float*)d_in[2];
  const float* Wih  = (const float*)d_in[3];
  const float* Whh  = (const float*)d_in[4];
  const float* bih  = (const float*)d_in[5];
  const float* bhh  = (const float*)d_in[6];
  const float* Wout = (const float*)d_in[7];
  const float* bout = (const float*)d_in[8];

  float* outp = (float*)d_out;                       // [T][B][OUT]
  float* hT   = outp + (size_t)TT * BB * OO;         // [B][H]
  float* cT   = hT + (size_t)BB * HH;                // [B][H]

  float* hring = (float*)d_ws;                       // 256 KB
  int*   flags = (int*)((char*)d_ws + (size_t)2 * BB * HH * sizeof(float));  // 1 KB

  // flags must be zero at every replay (graph-captured, runs each call)
  hipMemsetAsync(flags, 0, 8 * 32 * sizeof(int), stream);

  lstm_fused<<<dim3(256), dim3(512), 0, stream>>>(
      X, h0, c0, Wih, Whh, bih, bhh, Wout, bout, outp, hT, cT, hring, flags);
}

// Round 8
// 8156.542 us; speedup vs baseline: 5.6866x; 5.6866x over previous
//
#include <hip/hip_runtime.h>

#define TT 2048
#define BB 64
#define INF 32
#define HH 512
#define OO 32

__device__ __forceinline__ float sigm(float x) {
  return 1.f / (1.f + __expf(-x));
}
__device__ __forceinline__ float tanh_(float x) {
  float e = __expf(2.f * x);
  return 1.f - 2.f / (1.f + e);
}

// Coherent (L1/L2-bypassing) 16B load from the coherence point (IF$).
#define COH_LOAD4(dst, ptr)                                                  \
  asm volatile("global_load_dwordx4 %0, %1, off sc0 sc1"                     \
               : "=v"(dst) : "v"(ptr))

// Bounded spin: legit waits are ~µs; guard guarantees termination even under
// a protocol bug (wrong answer beats wedged GPU).
#define SPIN_LIMIT 20000

// LDS h-buffer: 8 batches x 64 k-groups, each group 8 floats + 4 pad words.
// Measured (R5/R7): SQ_LDS_BANK_CONFLICT == 0 with this layout.
#define HGRP 12
#define HB_STRIDE (64 * HGRP)  // 768 words per batch

// grid = 256 WGs: bg = blockIdx&7 (8 batches each), sl = blockIdx>>3 (16 h-indices each)
// block = 512 thr: wave rg = tid>>6 owns local rows [rg*8, rg*8+8); lane = k-chunk (8 k each)
// local row r in [0,64): gate gc = r>>4, jj = r&15, global row = gc*512 + sl*16 + jj
//
// RULE-20 NOTE: every index into v[] below MUST be compile-time constant
// after unrolling. A single runtime index (R5's "jb" form) sends the whole
// array to scratch: measured 176 GB WRITE_SIZE, 4.6x slowdown (R5/R6/R7).
__global__ __launch_bounds__(512, 2)
void lstm_fused(const float* __restrict__ X,
                const float* __restrict__ h0,
                const float* __restrict__ c0,
                const float* __restrict__ Wih,
                const float* __restrict__ Whh,
                const float* __restrict__ bih,
                const float* __restrict__ bhh,
                const float* __restrict__ Wout,
                const float* __restrict__ bout,
                float* __restrict__ outp,
                float* __restrict__ hT,
                float* __restrict__ cT,
                float* __restrict__ hring,   // [2][64][512] fp32 (coherent-point traffic)
                int* __restrict__ flags)     // [8][32] monotonic, zeroed per launch
{
  const int tid    = threadIdx.x;
  const int rg     = tid >> 6;
  const int lane   = tid & 63;
  const int bg     = blockIdx.x & 7;
  const int sl     = blockIdx.x >> 3;
  const int k0     = lane << 3;
  const int bglob0 = bg << 3;

  __shared__ float gsh[512];                 // gates [r(64)][b(8)]
  __shared__ float hlds[8 * HB_STRIDE];      // staged h, padded (24 KB)

  // ---- persistent weights in registers ----
  float w[8][8];
  float wih[8];
  const int ink = lane & 31;
#pragma unroll
  for (int rr = 0; rr < 8; ++rr) {
    int r = (rg << 3) + rr;
    int grow = ((r >> 4) << 9) + (sl << 4) + (r & 15);
    const float4* wp = (const float4*)(Whh + (size_t)grow * HH + k0);
    float4 a = wp[0], b4 = wp[1];
    w[rr][0] = a.x;  w[rr][1] = a.y;  w[rr][2] = a.z;  w[rr][3] = a.w;
    w[rr][4] = b4.x; w[rr][5] = b4.y; w[rr][6] = b4.z; w[rr][7] = b4.w;
    wih[rr] = Wih[grow * INF + ink];
  }
  float wout[8];
  {
    const float4* wp = (const float4*)(Wout + sl * HH + k0);
    float4 a = wp[0], b4 = wp[1];
    wout[0] = a.x;  wout[1] = a.y;  wout[2] = a.z;  wout[3] = a.w;
    wout[4] = b4.x; wout[5] = b4.y; wout[6] = b4.z; wout[7] = b4.w;
  }
  float bsum, bo = bout[sl];
  {
    int r = (rg << 3) + (lane >> 3);
    int grow = ((r >> 4) << 9) + (sl << 4) + (r & 15);
    bsum = bih[grow] + bhh[grow];
  }

  const bool owner = (tid < 128);
  const int ojj = tid >> 3, ob = tid & 7;
  const int hoff_owner = (bglob0 + ob) * HH + (sl << 4) + ojj;
  float cst = owner ? c0[hoff_owner] : 0.f;

  // cooperative-load mapping: thread handles batch lb, k-group lg
  const int lb = tid >> 6;
  const int lg = tid & 63;

  int* myflags = flags + (bg << 5);

  for (int t = 0; t < TT; ++t) {
    // ---- X prefetch only (runtime math in the ADDRESS, never the reg index) ----
    float xv[4];
    {
      const float* xr = X + (size_t)t * BB * INF + bglob0 * INF + ink;
      const int jb = (lane >= 32) ? 4 : 0;
#pragma unroll
      for (int j = 0; j < 4; ++j) xv[j] = xr[(jb + j) * INF];
    }

    // ---- wait for h_{t-1}: all 32 slices of my bg published step t-1 ----
    if (t > 0 && rg == 0) {
      int f = __hip_atomic_load(&myflags[lane & 31], __ATOMIC_RELAXED,
                                __HIP_MEMORY_SCOPE_AGENT);
      int guard = 0;
      while (__any(f < t)) {
        if (++guard > SPIN_LIMIT) break;   // uniform across wave
        __builtin_amdgcn_s_sleep(1);
        f = __hip_atomic_load(&myflags[lane & 31], __ATOMIC_RELAXED,
                              __HIP_MEMORY_SCOPE_AGENT);
      }
    }
    __syncthreads();  // barrier A: everyone sees flags>=t (via wave 0)

    // ---- cooperative coherent load of h_{t-1} (16 KB once per WG) ----
    {
      const float* hsrc = (t == 0) ? h0 : hring + (size_t)((t - 1) & 1) * BB * HH;
      const float* hp = hsrc + (size_t)(bglob0 + lb) * HH + (lg << 3);
      float4 ha, hb4;
      COH_LOAD4(ha, hp);
      COH_LOAD4(hb4, hp + 4);
      asm volatile("s_waitcnt vmcnt(0)" ::: "memory");
      __builtin_amdgcn_sched_barrier(0);
      float* dst = hlds + lb * HB_STRIDE + lg * HGRP;
      *(float4*)(dst)     = ha;
      *(float4*)(dst + 4) = hb4;
    }
    __syncthreads();  // barrier A2: staged h visible to all waves

    // ---- accumulators live ONLY from here to the gsh store ----
    float v[64];
#pragma unroll
    for (int i = 0; i < 64; ++i) v[i] = 0.f;
    float oacc = 0.f;

    // ---- recurrent dots: 8 batches x 8 rows x 8 k, LDS-fed register FMAs ----
#pragma unroll
    for (int b = 0; b < 8; ++b) {
      const float4* src = (const float4*)(hlds + b * HB_STRIDE + lane * HGRP);
      float4 a = src[0], b4 = src[1];
      float hk[8] = {a.x, a.y, a.z, a.w, b4.x, b4.y, b4.z, b4.w};
#pragma unroll
      for (int rr = 0; rr < 8; ++rr)
#pragma unroll
        for (int kk = 0; kk < 8; ++kk)
          v[rr * 8 + b] = __fmaf_rn(w[rr][kk], hk[kk], v[rr * 8 + b]);
      if (b == rg) {  // wave-uniform
#pragma unroll
        for (int kk = 0; kk < 8; ++kk) oacc = __fmaf_rn(hk[kk], wout[kk], oacc);
      }
    }

    // ---- input projection: COMPILE-TIME v-indices (R4 form, rule #20) ----
    if (lane < 32) {
#pragma unroll
      for (int j = 0; j < 4; ++j)
#pragma unroll
        for (int rr = 0; rr < 8; ++rr)
          v[rr * 8 + j] = __fmaf_rn(wih[rr], xv[j], v[rr * 8 + j]);
    } else {
#pragma unroll
      for (int j = 0; j < 4; ++j)
#pragma unroll
        for (int rr = 0; rr < 8; ++rr)
          v[rr * 8 + 4 + j] = __fmaf_rn(wih[rr], xv[j], v[rr * 8 + 4 + j]);
    }

    // ---- butterfly reduce over 64 k-chunk lanes; lane ends with idx==lane ----
#pragma unroll
    for (int i = 0; i < 32; ++i) {
      float a = v[i], b = v[i + 32];
      asm("v_permlane32_swap_b32 %0, %1" : "+v"(a), "+v"(b));
      v[i] = a + b;
    }
#pragma unroll
    for (int i = 0; i < 16; ++i) {
      float a = v[i], b = v[i + 16];
      asm("v_permlane16_swap_b32 %0, %1" : "+v"(a), "+v"(b));
      v[i] = a + b;
    }
#pragma unroll
    for (int s = 8; s >= 1; s >>= 1) {
      const bool hi = (lane & s) != 0;
#pragma unroll
      for (int i = 0; i < s; ++i) {
        float sent = hi ? v[i] : v[i + s];
        float keep = hi ? v[i + s] : v[i];
        v[i] = keep + __shfl_xor(sent, s, 64);
      }
    }
    gsh[(rg << 6) + lane] = v[0] + bsum;  // gates[r = rg*8+(lane>>3)][b = lane&7]
    __syncthreads();  // barrier B

    // ---- owners: nonlinearity, c/h update, coherent publish ----
    float* slotp = hring + (size_t)(t & 1) * BB * HH;
    if (owner) {
      float gi = gsh[(ojj << 3) + ob];
      float gf = gsh[((16 + ojj) << 3) + ob];
      float gg = gsh[((32 + ojj) << 3) + ob];
      float go = gsh[((48 + ojj) << 3) + ob];
      float i_ = sigm(gi), f_ = sigm(gf), g_ = tanh_(gg), o_ = sigm(go);
      cst = __fmaf_rn(f_, cst, i_ * g_);
      float hv = o_ * tanh_(cst);
      // write-through to coherence point; no fence needed
      __hip_atomic_store(&slotp[hoff_owner], hv, __ATOMIC_RELAXED,
                         __HIP_MEMORY_SCOPE_AGENT);
      if (t == TT - 1) { hT[hoff_owner] = hv; cT[hoff_owner] = cst; }
    }
    __syncthreads();  // barrier C: drains owners' stores (vmcnt(0) before s_barrier)
    if (tid == 0)
      __hip_atomic_store(&myflags[sl], t + 1, __ATOMIC_RELAXED,
                         __HIP_MEMORY_SCOPE_AGENT);

    // ---- deferred: out-projection reduce (off the inter-WG critical path) ----
#pragma unroll
    for (int s = 32; s >= 1; s >>= 1) oacc += __shfl_xor(oacc, s, 64);
    if (t > 0 && lane == 0)
      outp[(size_t)(t - 1) * BB * OO + (bglob0 + rg) * OO + sl] = oacc + bo;
  }

  // ---- final output projection for h_{TT-1} -> outputs[TT-1] ----
  if (rg == 0) {
    int f = __hip_atomic_load(&myflags[lane & 31], __ATOMIC_RELAXED,
                              __HIP_MEMORY_SCOPE_AGENT);
    int guard = 0;
    while (__any(f < TT)) {
      if (++guard > SPIN_LIMIT) break;
      __builtin_amdgcn_s_sleep(1);
      f = __hip_atomic_load(&myflags[lane & 31], __ATOMIC_RELAXED,
                            __HIP_MEMORY_SCOPE_AGENT);
    }
  }
  __syncthreads();
  {
    const float* hsrc = hring + (size_t)((TT - 1) & 1) * BB * HH;
    const float* hb = hsrc + (size_t)(bglob0 + rg) * HH + k0;
    float4 a, b4;
    COH_LOAD4(a, hb);
    COH_LOAD4(b4, hb + 4);
    asm volatile("s_waitcnt vmcnt(0)" ::: "memory");
    __builtin_amdgcn_sched_barrier(0);
    float oacc = a.x * wout[0] + a.y * wout[1] + a.z * wout[2] + a.w * wout[3]
               + b4.x * wout[4] + b4.y * wout[5] + b4.z * wout[6] + b4.w * wout[7];
#pragma unroll
    for (int s = 32; s >= 1; s >>= 1) oacc += __shfl_xor(oacc, s, 64);
    if (lane == 0)
      outp[(size_t)(TT - 1) * BB * OO + (bglob0 + rg) * OO + sl] = oacc + bo;
  }
}

extern "C" void kernel_launch(void* const* d_in, const int* in_sizes, int n_in,
                              void* d_out, int out_size, void* d_ws, size_t ws_size,
                              hipStream_t stream) {
  const float* X    = (const float*)d_in[0];
  const float* h0   = (const float*)d_in[1];
  const float* c0   = (const float*)d_in[2];
  const float* Wih  = (const float*)d_in[3];
  const float* Whh  = (const float*)d_in[4];
  const float* bih  = (const float*)d_in[5];
  const float* bhh  = (const float*)d_in[6];
  const float* Wout = (const float*)d_in[7];
  const float* bout = (const float*)d_in[8];

  float* outp = (float*)d_out;                       // [T][B][OUT]
  float* hT   = outp + (size_t)TT * BB * OO;         // [B][H]
  float* cT   = hT + (size_t)BB * HH;                // [B][H]

  float* hring = (float*)d_ws;                       // 256 KB
  int*   flags = (int*)((char*)d_ws + (size_t)2 * BB * HH * sizeof(float));  // 1 KB

  // flags must be zero at every replay (graph-captured, runs each call)
  hipMemsetAsync(flags, 0, 8 * 32 * sizeof(int), stream);

  lstm_fused<<<dim3(256), dim3(512), 0, stream>>>(
      X, h0, c0, Wih, Whh, bih, bhh, Wout, bout, outp, hT, cT, hring, flags);
}